// Round 1
// baseline (448.989 us; speedup 1.0000x reference)
//
#include <hip/hip_runtime.h>
#include <hip/hip_bf16.h>
#include <math.h>

// Problem constants
#define BB 256
#define TT 256
#define EE 384
#define HH 6
#define DD 64

typedef __attribute__((ext_vector_type(8))) short bf16x8;
typedef __attribute__((ext_vector_type(4))) float f32x4;

__device__ inline unsigned short f2bf(float f) {
  unsigned int u = __builtin_bit_cast(unsigned int, f);
  u += 0x7fffu + ((u >> 16) & 1u);
  return (unsigned short)(u >> 16);
}

__device__ __forceinline__ void g2l16(const unsigned short* g, unsigned short* l) {
  // async global -> LDS, 16B per lane; LDS dest = wave-uniform base + lane*16
  __builtin_amdgcn_global_load_lds(
      (const __attribute__((address_space(1))) void*)g,
      (__attribute__((address_space(3))) void*)l, 16, 0, 0);
}

// ---------------------------------------------------------------------------
// Kernel 0: fp32 -> bf16 convert (x -> xb)
// ---------------------------------------------------------------------------
__global__ __launch_bounds__(256) void cvt_kernel(const float* __restrict__ x,
                                                  unsigned short* __restrict__ xb,
                                                  int n4) {
  int i = blockIdx.x * 256 + threadIdx.x;
  if (i < n4) {
    float4 f = ((const float4*)x)[i];
    ushort4 o;
    o.x = f2bf(f.x); o.y = f2bf(f.y); o.z = f2bf(f.z); o.w = f2bf(f.w);
    ((ushort4*)xb)[i] = o;
  }
}

// ---------------------------------------------------------------------------
// Kernel 0b: weight prep. Wt[1536][384] bf16:
//   rows 0..1151:  Wt[mat*384 + h*64 + d][e] = W{q,k,v}[h][e][d]
//   rows 1152..1535: Wt[1152 + n][k] = Wo[k][n]
// ---------------------------------------------------------------------------
__global__ __launch_bounds__(256) void wprep_kernel(const float* __restrict__ Wq,
                                                    const float* __restrict__ Wk,
                                                    const float* __restrict__ Wv,
                                                    const float* __restrict__ Wo,
                                                    unsigned short* __restrict__ Wt) {
  int idx = blockIdx.x * 256 + threadIdx.x;
  if (idx >= 1536 * 384) return;
  int n = idx / 384, k = idx % 384;
  float val;
  if (n < 1152) {
    int mat = n / 384;
    int c = n % 384;
    int h = c >> 6, d = c & 63;
    const float* W = (mat == 0) ? Wq : (mat == 1 ? Wk : Wv);
    val = W[((size_t)h * EE + k) * DD + d];
  } else {
    int c = n - 1152;
    val = Wo[(size_t)k * EE + c];
  }
  Wt[idx] = f2bf(val);
}

// ---------------------------------------------------------------------------
// Kernel 1: fused QKV GEMM.  C[65536, 1152] = xb @ [Wq|Wk|Wv]  (bf16 MFMA)
// 128x128 tile, BK=64, global_load_lds(16B) staging, XOR-swizzled LDS.
// n-tiles 0..2 -> q [B,H,T,D] (pre-scaled by 1/sqrt(D)); 3..5 -> k;
// 6..8 -> v transposed [B,H,D,T].
// ---------------------------------------------------------------------------
__global__ __launch_bounds__(256) void qkv128_kernel(const unsigned short* __restrict__ A,
                                                     const unsigned short* __restrict__ Wt,
                                                     unsigned short* __restrict__ q,
                                                     unsigned short* __restrict__ k,
                                                     unsigned short* __restrict__ v) {
  const int bx = blockIdx.x;            // n-tile (0..8)
  const int m0 = blockIdx.y * 128;
  const int n0 = bx * 128;

  __shared__ char smem[32768];
  unsigned short* As = (unsigned short*)smem;            // [128][64] swizzled
  unsigned short* Bs = (unsigned short*)(smem + 16384);  // [128][64] swizzled
  unsigned short* bounce = (unsigned short*)smem;        // [64][136] after mainloop

  const int tid = threadIdx.x;
  const int wave = tid >> 6, lane = tid & 63;
  const int l15 = lane & 15, quad = lane >> 4;
  const int wm = (wave & 1) * 64, wn = (wave >> 1) * 64;
  const int xs = l15 & 7;

  f32x4 acc[4][4];
#pragma unroll
  for (int i = 0; i < 4; ++i)
#pragma unroll
    for (int j = 0; j < 4; ++j) acc[i][j] = (f32x4){0.f, 0.f, 0.f, 0.f};

  const int rl_base = wave * 32 + (lane >> 3);
  const int sb = lane & 7;

  for (int k0 = 0; k0 < EE; k0 += 64) {
    __syncthreads();
#pragma unroll
    for (int i = 0; i < 4; ++i) {
      int rl = rl_base + i * 8;
      int gcb = sb ^ (rl & 7);
      g2l16(A + (size_t)(m0 + rl) * EE + k0 + gcb * 8, &As[(wave * 32 + i * 8) * 64]);
    }
#pragma unroll
    for (int i = 0; i < 4; ++i) {
      int rl = rl_base + i * 8;
      int gcb = sb ^ (rl & 7);
      g2l16(Wt + (size_t)(n0 + rl) * EE + k0 + gcb * 8, &Bs[(wave * 32 + i * 8) * 64]);
    }
    __syncthreads();
#pragma unroll
    for (int kc = 0; kc < 2; ++kc) {
      bf16x8 af[4], bfr[4];
#pragma unroll
      for (int mi = 0; mi < 4; ++mi)
        af[mi] = *(const bf16x8*)&As[(wm + mi * 16 + l15) * 64 + ((kc * 4 + quad) ^ xs) * 8];
#pragma unroll
      for (int ni = 0; ni < 4; ++ni)
        bfr[ni] = *(const bf16x8*)&Bs[(wn + ni * 16 + l15) * 64 + ((kc * 4 + quad) ^ xs) * 8];
#pragma unroll
      for (int mi = 0; mi < 4; ++mi)
#pragma unroll
        for (int ni = 0; ni < 4; ++ni)
          acc[mi][ni] = __builtin_amdgcn_mfma_f32_16x16x32_bf16(af[mi], bfr[ni], acc[mi][ni], 0, 0, 0);
    }
  }

  const int b = m0 >> 8;          // 128-row tile stays within one batch (T=256)
  const int t0 = m0 & 255;

  if (bx < 6) {
    // q / k : [B,H,T,D].  q gets the softmax scale folded in (fp32, pre-round).
    unsigned short* outp = (bx < 3) ? q : k;
    const float qs = (bx < 3) ? 0.125f : 1.0f;
    const int cmbase = n0 - (bx < 3 ? 0 : 384);
#pragma unroll
    for (int ni = 0; ni < 4; ++ni) {
      int c = cmbase + wn + ni * 16 + l15;   // 0..383 within mat
      int h = c >> 6, d = c & 63;
#pragma unroll
      for (int mi = 0; mi < 4; ++mi)
#pragma unroll
        for (int r = 0; r < 4; ++r) {
          int t = t0 + wm + mi * 16 + quad * 4 + r;
          outp[(((size_t)b * HH + h) * TT + t) * DD + d] = f2bf(acc[mi][ni][r] * qs);
        }
    }
  } else {
    // v : transpose to [B,H,D,T] via LDS bounce, one 64-col half (one head) per pass
#pragma unroll
    for (int pass = 0; pass < 2; ++pass) {
      __syncthreads();
      if ((wave >> 1) == pass) {
#pragma unroll
        for (int ni = 0; ni < 4; ++ni) {
          int cl = ni * 16 + l15;            // d within head
#pragma unroll
          for (int mi = 0; mi < 4; ++mi)
#pragma unroll
            for (int r = 0; r < 4; ++r) {
              int rloc = wm + mi * 16 + quad * 4 + r;   // t within tile
              bounce[cl * 136 + rloc] = f2bf(acc[mi][ni][r]);
            }
        }
      }
      __syncthreads();
      int h = (bx - 6) * 2 + pass;
      int d = tid >> 2;
      int tb = (tid & 3) * 32;
      unsigned short* vdst = v + (((size_t)b * HH + h) * DD + d) * TT + t0 + tb;
      const unsigned short* bsrc = &bounce[d * 136 + tb];
#pragma unroll
      for (int j = 0; j < 4; ++j)
        *(uint4*)(vdst + j * 8) = *(const uint4*)(bsrc + j * 8);
    }
  }
}

// ---------------------------------------------------------------------------
// Kernel 2: flash-style causal attention.
// R2 changes vs R1:
//   - Q fragments hoisted to registers (Qs LDS buffer deleted; LDS 37->27.6 KB)
//   - T14 async-STAGE split: next K/V tile global loads issued BEFORE compute
//     (into regs), ds_write after the post-compute barrier -> latency hidden
//   - s_setprio(1) around MFMA clusters (T5)
//   - softmax scale folded into q upstream (one VALU mul/row removed)
// ---------------------------------------------------------------------------
__global__ __launch_bounds__(256) void attn_kernel(const unsigned short* __restrict__ q,
                                                   const unsigned short* __restrict__ k,
                                                   const unsigned short* __restrict__ v,
                                                   unsigned short* __restrict__ att) {
  const int bh = blockIdx.x;
  const int q0 = blockIdx.y * 64;
  const int b = bh / HH, h = bh % HH;

  __shared__ unsigned short Ks[64 * 72];
  __shared__ unsigned short Vt[64 * 72];
  __shared__ unsigned short Ps[64 * 72];

  const int tid = threadIdx.x;
  const int wave = tid >> 6, lane = tid & 63;
  const int l15 = lane & 15, quad = lane >> 4;
  const int koff = quad * 8;

  // staging coords: 4 threads per row, 32B each -> fully coalesced 128B rows
  const int sr = tid >> 2, sc = (tid & 3) * 16;
  const unsigned short* kbase = k + ((size_t)bh * TT + sr) * DD + sc;
  const unsigned short* vbase = v + ((size_t)bh * DD + sr) * TT + sc;

  // Q fragments: wave-private, loop-invariant -> load once from global
  bf16x8 aq[2];
  {
    const unsigned short* qrow =
        q + ((size_t)bh * TT + q0 + wave * 16 + l15) * DD + koff;
    aq[0] = *(const bf16x8*)(qrow);
    aq[1] = *(const bf16x8*)(qrow + 32);
  }

  // prologue: stage tile j0 = 0
  uint4 kr0 = *(const uint4*)(kbase);
  uint4 kr1 = *(const uint4*)(kbase + 8);
  uint4 vr0 = *(const uint4*)(vbase);
  uint4 vr1 = *(const uint4*)(vbase + 8);
  *(uint4*)&Ks[sr * 72 + sc]     = kr0;
  *(uint4*)&Ks[sr * 72 + sc + 8] = kr1;
  *(uint4*)&Vt[sr * 72 + sc]     = vr0;
  *(uint4*)&Vt[sr * 72 + sc + 8] = vr1;
  __syncthreads();

  f32x4 o_acc[4] = {{0.f,0.f,0.f,0.f},{0.f,0.f,0.f,0.f},{0.f,0.f,0.f,0.f},{0.f,0.f,0.f,0.f}};
  float m_run[4] = {-INFINITY, -INFINITY, -INFINITY, -INFINITY};
  float l_run[4] = {0.f, 0.f, 0.f, 0.f};

  for (int j0 = 0; j0 <= q0; j0 += 64) {
    const bool has_next = (j0 + 64 <= q0);
    if (has_next) {
      // T14: issue next tile's loads now; LDS write happens after the barrier
      const unsigned short* kn = kbase + (size_t)(j0 + 64) * DD;
      const unsigned short* vn = vbase + (j0 + 64);
      kr0 = *(const uint4*)(kn);
      kr1 = *(const uint4*)(kn + 8);
      vr0 = *(const uint4*)(vn);
      vr1 = *(const uint4*)(vn + 8);
    }

    // QK^T (q pre-scaled by 1/8 upstream)
    f32x4 s_acc[4] = {{0.f,0.f,0.f,0.f},{0.f,0.f,0.f,0.f},{0.f,0.f,0.f,0.f},{0.f,0.f,0.f,0.f}};
    __builtin_amdgcn_s_setprio(1);
#pragma unroll
    for (int kc = 0; kc < 2; ++kc) {
#pragma unroll
      for (int ct = 0; ct < 4; ++ct) {
        bf16x8 bb = *(const bf16x8*)&Ks[(ct * 16 + l15) * 72 + kc * 32 + koff];
        s_acc[ct] = __builtin_amdgcn_mfma_f32_16x16x32_bf16(aq[kc], bb, s_acc[ct], 0, 0, 0);
      }
    }
    __builtin_amdgcn_s_setprio(0);

    const bool diag = (j0 == q0);
    const int rowbase = q0 + wave * 16 + quad * 4;
#pragma unroll
    for (int r = 0; r < 4; ++r) {
      int qrow = rowbase + r;
      float sv[4];
#pragma unroll
      for (int ct = 0; ct < 4; ++ct) {
        float s = s_acc[ct][r];
        if (diag && (j0 + ct * 16 + l15) > qrow) s = -INFINITY;
        sv[ct] = s;
      }
      float mt = fmaxf(fmaxf(sv[0], sv[1]), fmaxf(sv[2], sv[3]));
      mt = fmaxf(mt, __shfl_xor(mt, 1));
      mt = fmaxf(mt, __shfl_xor(mt, 2));
      mt = fmaxf(mt, __shfl_xor(mt, 4));
      mt = fmaxf(mt, __shfl_xor(mt, 8));
      float mnew = fmaxf(m_run[r], mt);
      float alpha = __expf(m_run[r] - mnew);
      float psum = 0.f;
      int prow = (wave * 16 + quad * 4 + r) * 72;
#pragma unroll
      for (int ct = 0; ct < 4; ++ct) {
        float p = __expf(sv[ct] - mnew);
        psum += p;
        Ps[prow + ct * 16 + l15] = f2bf(p);
      }
      psum += __shfl_xor(psum, 1);
      psum += __shfl_xor(psum, 2);
      psum += __shfl_xor(psum, 4);
      psum += __shfl_xor(psum, 8);
      l_run[r] = l_run[r] * alpha + psum;
      m_run[r] = mnew;
#pragma unroll
      for (int dt = 0; dt < 4; ++dt) o_acc[dt][r] *= alpha;
    }

    // PV  (Ps rows are wave-private: no barrier needed, lgkmcnt orders within-wave)
    __builtin_amdgcn_s_setprio(1);
#pragma unroll
    for (int kc = 0; kc < 2; ++kc) {
      bf16x8 a = *(const bf16x8*)&Ps[(wave * 16 + l15) * 72 + kc * 32 + koff];
#pragma unroll
      for (int dt = 0; dt < 4; ++dt) {
        bf16x8 bb = *(const bf16x8*)&Vt[(dt * 16 + l15) * 72 + kc * 32 + koff];
        o_acc[dt] = __builtin_amdgcn_mfma_f32_16x16x32_bf16(a, bb, o_acc[dt], 0, 0, 0);
      }
    }
    __builtin_amdgcn_s_setprio(0);

    if (has_next) {
      __syncthreads();   // everyone done reading Ks/Vt
      *(uint4*)&Ks[sr * 72 + sc]     = kr0;
      *(uint4*)&Ks[sr * 72 + sc + 8] = kr1;
      *(uint4*)&Vt[sr * 72 + sc]     = vr0;
      *(uint4*)&Vt[sr * 72 + sc + 8] = vr1;
      __syncthreads();   // next tile ready
    }
  }

#pragma unroll
  for (int dt = 0; dt < 4; ++dt) {
#pragma unroll
    for (int r = 0; r < 4; ++r) {
      int row = wave * 16 + quad * 4 + r;
      int t = q0 + row;
      int d = dt * 16 + l15;
      float o = o_acc[dt][r] / l_run[r];
      att[(((size_t)b * TT + t) * HH + h) * DD + d] = f2bf(o);
    }
  }
}

// ---------------------------------------------------------------------------
// Kernel 3: output projection  out[M,384] = att @ Wo + bo  (same GEMM template)
// ---------------------------------------------------------------------------
__global__ __launch_bounds__(256) void oproj128_kernel(const unsigned short* __restrict__ A,
                                                       const unsigned short* __restrict__ Wot,
                                                       const float* __restrict__ bo,
                                                       float* __restrict__ out) {
  const int n0 = blockIdx.x * 128;
  const int m0 = blockIdx.y * 128;

  __shared__ char smem[32768];
  unsigned short* As = (unsigned short*)smem;
  unsigned short* Bs = (unsigned short*)(smem + 16384);

  const int tid = threadIdx.x;
  const int wave = tid >> 6, lane = tid & 63;
  const int l15 = lane & 15, quad = lane >> 4;
  const int wm = (wave & 1) * 64, wn = (wave >> 1) * 64;
  const int xs = l15 & 7;

  f32x4 acc[4][4];
#pragma unroll
  for (int i = 0; i < 4; ++i)
#pragma unroll
    for (int j = 0; j < 4; ++j) acc[i][j] = (f32x4){0.f, 0.f, 0.f, 0.f};

  const int rl_base = wave * 32 + (lane >> 3);
  const int sb = lane & 7;

  for (int k0 = 0; k0 < EE; k0 += 64) {
    __syncthreads();
#pragma unroll
    for (int i = 0; i < 4; ++i) {
      int rl = rl_base + i * 8;
      int gcb = sb ^ (rl & 7);
      g2l16(A + (size_t)(m0 + rl) * EE + k0 + gcb * 8, &As[(wave * 32 + i * 8) * 64]);
    }
#pragma unroll
    for (int i = 0; i < 4; ++i) {
      int rl = rl_base + i * 8;
      int gcb = sb ^ (rl & 7);
      g2l16(Wot + (size_t)(n0 + rl) * EE + k0 + gcb * 8, &Bs[(wave * 32 + i * 8) * 64]);
    }
    __syncthreads();
#pragma unroll
    for (int kc = 0; kc < 2; ++kc) {
      bf16x8 af[4], bfr[4];
#pragma unroll
      for (int mi = 0; mi < 4; ++mi)
        af[mi] = *(const bf16x8*)&As[(wm + mi * 16 + l15) * 64 + ((kc * 4 + quad) ^ xs) * 8];
#pragma unroll
      for (int ni = 0; ni < 4; ++ni)
        bfr[ni] = *(const bf16x8*)&Bs[(wn + ni * 16 + l15) * 64 + ((kc * 4 + quad) ^ xs) * 8];
#pragma unroll
      for (int mi = 0; mi < 4; ++mi)
#pragma unroll
        for (int ni = 0; ni < 4; ++ni)
          acc[mi][ni] = __builtin_amdgcn_mfma_f32_16x16x32_bf16(af[mi], bfr[ni], acc[mi][ni], 0, 0, 0);
    }
  }

#pragma unroll
  for (int ni = 0; ni < 4; ++ni) {
    int c = n0 + wn + ni * 16 + l15;
    float bias = bo[c];
#pragma unroll
    for (int mi = 0; mi < 4; ++mi)
#pragma unroll
      for (int r = 0; r < 4; ++r) {
        int m = m0 + wm + mi * 16 + quad * 4 + r;
        out[(size_t)m * EE + c] = acc[mi][ni][r] + bias;
      }
  }
}

// ---------------------------------------------------------------------------
extern "C" void kernel_launch(void* const* d_in, const int* in_sizes, int n_in,
                              void* d_out, int out_size, void* d_ws, size_t ws_size,
                              hipStream_t stream) {
  const float* x  = (const float*)d_in[0];
  const float* Wq = (const float*)d_in[1];
  const float* Wk = (const float*)d_in[2];
  const float* Wv = (const float*)d_in[3];
  const float* Wo = (const float*)d_in[4];
  const float* bo = (const float*)d_in[5];
  float* out = (float*)d_out;

  char* ws = (char*)d_ws;
  const size_t SZ = (size_t)BB * TT * EE * 2;       // 48 MiB
  const size_t SQ = (size_t)BB * HH * TT * DD * 2;  // 48 MiB
  unsigned short* xb = (unsigned short*)ws;          // [B*T, E] bf16
  unsigned short* q  = (unsigned short*)(ws + SZ);
  unsigned short* k  = (unsigned short*)(ws + SZ + SQ);
  unsigned short* v  = (unsigned short*)(ws + SZ + 2 * SQ);
  unsigned short* Wt = (unsigned short*)(ws + SZ + 3 * SQ);  // [1536][384] bf16
  unsigned short* att = xb;  // xb dead after qkv; reuse for attention output

  int n4 = (BB * TT * EE) / 4;
  cvt_kernel<<<(n4 + 255) / 256, 256, 0, stream>>>(x, xb, n4);
  wprep_kernel<<<(1536 * 384 + 255) / 256, 256, 0, stream>>>(Wq, Wk, Wv, Wo, Wt);
  qkv128_kernel<<<dim3(9, (BB * TT) / 128), 256, 0, stream>>>(xb, Wt, q, k, v);
  attn_kernel<<<dim3(BB * HH, TT / 64), 256, 0, stream>>>(q, k, v, att);
  oproj128_kernel<<<dim3(3, (BB * TT) / 128), 256, 0, stream>>>(att, Wt + 1152 * 384, bo, out);
}

// Round 2
// 358.236 us; speedup vs baseline: 1.2533x; 1.2533x over previous
//
#include <hip/hip_runtime.h>
#include <hip/hip_bf16.h>
#include <math.h>

// Problem constants
#define BB 256
#define TT 256
#define EE 384
#define HH 6
#define DD 64

typedef __attribute__((ext_vector_type(8))) short bf16x8;
typedef __attribute__((ext_vector_type(4))) float f32x4;

__device__ inline unsigned short f2bf(float f) {
  unsigned int u = __builtin_bit_cast(unsigned int, f);
  u += 0x7fffu + ((u >> 16) & 1u);
  return (unsigned short)(u >> 16);
}

__device__ __forceinline__ void g2l16(const unsigned short* g, unsigned short* l) {
  // async global -> LDS, 16B per lane; LDS dest = wave-uniform base + lane*16
  __builtin_amdgcn_global_load_lds(
      (const __attribute__((address_space(1))) void*)g,
      (__attribute__((address_space(3))) void*)l, 16, 0, 0);
}

// ---------------------------------------------------------------------------
// Kernel 0: fp32 -> bf16 convert (x -> xb)
// ---------------------------------------------------------------------------
__global__ __launch_bounds__(256) void cvt_kernel(const float* __restrict__ x,
                                                  unsigned short* __restrict__ xb,
                                                  int n4) {
  int i = blockIdx.x * 256 + threadIdx.x;
  if (i < n4) {
    float4 f = ((const float4*)x)[i];
    ushort4 o;
    o.x = f2bf(f.x); o.y = f2bf(f.y); o.z = f2bf(f.z); o.w = f2bf(f.w);
    ((ushort4*)xb)[i] = o;
  }
}

// ---------------------------------------------------------------------------
// Kernel 0b: weight prep. Wt[1536][384] bf16:
//   rows 0..1151:  Wt[mat*384 + h*64 + d][e] = W{q,k,v}[h][e][d]
//   rows 1152..1535: Wt[1152 + n][k] = Wo[k][n]
// ---------------------------------------------------------------------------
__global__ __launch_bounds__(256) void wprep_kernel(const float* __restrict__ Wq,
                                                    const float* __restrict__ Wk,
                                                    const float* __restrict__ Wv,
                                                    const float* __restrict__ Wo,
                                                    unsigned short* __restrict__ Wt) {
  int idx = blockIdx.x * 256 + threadIdx.x;
  if (idx >= 1536 * 384) return;
  int n = idx / 384, k = idx % 384;
  float val;
  if (n < 1152) {
    int mat = n / 384;
    int c = n % 384;
    int h = c >> 6, d = c & 63;
    const float* W = (mat == 0) ? Wq : (mat == 1 ? Wk : Wv);
    val = W[((size_t)h * EE + k) * DD + d];
  } else {
    int c = n - 1152;
    val = Wo[(size_t)k * EE + c];
  }
  Wt[idx] = f2bf(val);
}

// ---------------------------------------------------------------------------
// Shared GEMM-tile macros: 128x128 tile, BK=64, XOR-swizzled LDS,
// double-buffered (2-phase pipeline, T3-minimum recipe).
//   STAGE_T(buf, k0, Bsrc): issue 8 global_load_lds(16B) into buffer `buf`
//   COMPUTE_T(buf): 8 ds_read_b128 + 32 MFMA on buffer `buf`
// Buffer layout in smem: buf b -> As @ b*32768, Bs @ b*32768+16384 (bytes).
// ---------------------------------------------------------------------------
#define STAGE_T(buf, k0, Bsrc)                                                  \
  do {                                                                          \
    unsigned short* As_ = (unsigned short*)(smem + (buf) * 32768);              \
    unsigned short* Bs_ = As_ + 8192;                                           \
    _Pragma("unroll") for (int i = 0; i < 4; ++i) {                             \
      int rl = rl_base + i * 8;                                                 \
      int gcb = sb ^ (rl & 7);                                                  \
      g2l16(A + (size_t)(m0 + rl) * EE + (k0) + gcb * 8,                        \
            &As_[(wave * 32 + i * 8) * 64]);                                    \
    }                                                                           \
    _Pragma("unroll") for (int i = 0; i < 4; ++i) {                             \
      int rl = rl_base + i * 8;                                                 \
      int gcb = sb ^ (rl & 7);                                                  \
      g2l16((Bsrc) + (size_t)(n0 + rl) * EE + (k0) + gcb * 8,                   \
            &Bs_[(wave * 32 + i * 8) * 64]);                                    \
    }                                                                           \
  } while (0)

#define COMPUTE_T(buf)                                                          \
  do {                                                                          \
    const unsigned short* As_ = (const unsigned short*)(smem + (buf) * 32768);  \
    const unsigned short* Bs_ = As_ + 8192;                                     \
    _Pragma("unroll") for (int kc = 0; kc < 2; ++kc) {                          \
      bf16x8 af[4], bfr[4];                                                     \
      _Pragma("unroll") for (int mi = 0; mi < 4; ++mi)                          \
          af[mi] = *(const bf16x8*)&As_[(wm + mi * 16 + l15) * 64 +             \
                                        ((kc * 4 + quad) ^ xs) * 8];            \
      _Pragma("unroll") for (int ni = 0; ni < 4; ++ni)                          \
          bfr[ni] = *(const bf16x8*)&Bs_[(wn + ni * 16 + l15) * 64 +            \
                                         ((kc * 4 + quad) ^ xs) * 8];           \
      _Pragma("unroll") for (int mi = 0; mi < 4; ++mi)                          \
          _Pragma("unroll") for (int ni = 0; ni < 4; ++ni)                      \
              acc[mi][ni] = __builtin_amdgcn_mfma_f32_16x16x32_bf16(            \
                  af[mi], bfr[ni], acc[mi][ni], 0, 0, 0);                       \
    }                                                                           \
  } while (0)

// ---------------------------------------------------------------------------
// Kernel 1: fused QKV GEMM.  C[65536, 1152] = xb @ [Wq|Wk|Wv]  (bf16 MFMA)
// XCD-swizzled 1-D grid (4608 = 8 XCD * 64 m-tiles * 9 n-tiles): each XCD owns
// 64 contiguous m-tiles, iterating all 9 n-tiles per m-tile -> A-tile stays in
// that XCD's L2 across its 9 consumers.
// n-tiles 0..2 -> q [B,H,T,D] (pre-scaled by 1/sqrt(D)); 3..5 -> k;
// 6..8 -> v transposed [B,H,D,T].
// ---------------------------------------------------------------------------
__global__ __launch_bounds__(256, 2) void qkv128_kernel(const unsigned short* __restrict__ A,
                                                        const unsigned short* __restrict__ Wt,
                                                        unsigned short* __restrict__ q,
                                                        unsigned short* __restrict__ k,
                                                        unsigned short* __restrict__ v) {
  // bijective XCD swizzle: L = xcd + 8*j, j = mtile_local*9 + bx
  const int L = blockIdx.x;
  const int xcd = L & 7;
  const int j = L >> 3;                 // 0..575
  const int mt = xcd * 64 + j / 9;      // 0..511
  const int bx = j % 9;                 // n-tile
  const int m0 = mt * 128;
  const int n0 = bx * 128;

  __shared__ char smem[65536];
  unsigned short* bounce = (unsigned short*)smem;  // [64][136] after mainloop

  const int tid = threadIdx.x;
  const int wave = tid >> 6, lane = tid & 63;
  const int l15 = lane & 15, quad = lane >> 4;
  const int wm = (wave & 1) * 64, wn = (wave >> 1) * 64;
  const int xs = l15 & 7;

  f32x4 acc[4][4];
#pragma unroll
  for (int i = 0; i < 4; ++i)
#pragma unroll
    for (int jj = 0; jj < 4; ++jj) acc[i][jj] = (f32x4){0.f, 0.f, 0.f, 0.f};

  const int rl_base = wave * 32 + (lane >> 3);
  const int sb = lane & 7;

  // 2-phase pipeline: prologue stage, then {prefetch next | compute cur}
  STAGE_T(0, 0, Wt);
  __syncthreads();                       // vmcnt(0) drain + barrier
#pragma unroll
  for (int it = 0; it < 6; ++it) {
    if (it < 5) STAGE_T((it & 1) ^ 1, (it + 1) * 64, Wt);
    COMPUTE_T(it & 1);
    __syncthreads();                     // reads of cur done; next buf landed
  }

  const int b = m0 >> 8;          // 128-row tile stays within one batch (T=256)
  const int t0 = m0 & 255;

  if (bx < 6) {
    // q / k : [B,H,T,D].  q gets the softmax scale folded in (fp32, pre-round).
    unsigned short* outp = (bx < 3) ? q : k;
    const float qs = (bx < 3) ? 0.125f : 1.0f;
    const int cmbase = n0 - (bx < 3 ? 0 : 384);
#pragma unroll
    for (int ni = 0; ni < 4; ++ni) {
      int c = cmbase + wn + ni * 16 + l15;   // 0..383 within mat
      int h = c >> 6, d = c & 63;
#pragma unroll
      for (int mi = 0; mi < 4; ++mi)
#pragma unroll
        for (int r = 0; r < 4; ++r) {
          int t = t0 + wm + mi * 16 + quad * 4 + r;
          outp[(((size_t)b * HH + h) * TT + t) * DD + d] = f2bf(acc[mi][ni][r] * qs);
        }
    }
  } else {
    // v : transpose to [B,H,D,T] via LDS bounce, one 64-col half (one head) per pass
#pragma unroll
    for (int pass = 0; pass < 2; ++pass) {
      __syncthreads();
      if ((wave >> 1) == pass) {
#pragma unroll
        for (int ni = 0; ni < 4; ++ni) {
          int cl = ni * 16 + l15;            // d within head
#pragma unroll
          for (int mi = 0; mi < 4; ++mi)
#pragma unroll
            for (int r = 0; r < 4; ++r) {
              int rloc = wm + mi * 16 + quad * 4 + r;   // t within tile
              bounce[cl * 136 + rloc] = f2bf(acc[mi][ni][r]);
            }
        }
      }
      __syncthreads();
      int h = (bx - 6) * 2 + pass;
      int d = tid >> 2;
      int tb = (tid & 3) * 32;
      unsigned short* vdst = v + (((size_t)b * HH + h) * DD + d) * TT + t0 + tb;
      const unsigned short* bsrc = &bounce[d * 136 + tb];
#pragma unroll
      for (int jj = 0; jj < 4; ++jj)
        *(uint4*)(vdst + jj * 8) = *(const uint4*)(bsrc + jj * 8);
    }
  }
}

// ---------------------------------------------------------------------------
// Kernel 2: flash-style causal attention (unchanged this round).
// ---------------------------------------------------------------------------
__global__ __launch_bounds__(256) void attn_kernel(const unsigned short* __restrict__ q,
                                                   const unsigned short* __restrict__ k,
                                                   const unsigned short* __restrict__ v,
                                                   unsigned short* __restrict__ att) {
  const int bh = blockIdx.x;
  const int q0 = blockIdx.y * 64;
  const int b = bh / HH, h = bh % HH;

  __shared__ unsigned short Ks[64 * 72];
  __shared__ unsigned short Vt[64 * 72];
  __shared__ unsigned short Ps[64 * 72];

  const int tid = threadIdx.x;
  const int wave = tid >> 6, lane = tid & 63;
  const int l15 = lane & 15, quad = lane >> 4;
  const int koff = quad * 8;

  // staging coords: 4 threads per row, 32B each -> fully coalesced 128B rows
  const int sr = tid >> 2, sc = (tid & 3) * 16;
  const unsigned short* kbase = k + ((size_t)bh * TT + sr) * DD + sc;
  const unsigned short* vbase = v + ((size_t)bh * DD + sr) * TT + sc;

  // Q fragments: wave-private, loop-invariant -> load once from global
  bf16x8 aq[2];
  {
    const unsigned short* qrow =
        q + ((size_t)bh * TT + q0 + wave * 16 + l15) * DD + koff;
    aq[0] = *(const bf16x8*)(qrow);
    aq[1] = *(const bf16x8*)(qrow + 32);
  }

  // prologue: stage tile j0 = 0
  uint4 kr0 = *(const uint4*)(kbase);
  uint4 kr1 = *(const uint4*)(kbase + 8);
  uint4 vr0 = *(const uint4*)(vbase);
  uint4 vr1 = *(const uint4*)(vbase + 8);
  *(uint4*)&Ks[sr * 72 + sc]     = kr0;
  *(uint4*)&Ks[sr * 72 + sc + 8] = kr1;
  *(uint4*)&Vt[sr * 72 + sc]     = vr0;
  *(uint4*)&Vt[sr * 72 + sc + 8] = vr1;
  __syncthreads();

  f32x4 o_acc[4] = {{0.f,0.f,0.f,0.f},{0.f,0.f,0.f,0.f},{0.f,0.f,0.f,0.f},{0.f,0.f,0.f,0.f}};
  float m_run[4] = {-INFINITY, -INFINITY, -INFINITY, -INFINITY};
  float l_run[4] = {0.f, 0.f, 0.f, 0.f};

  for (int j0 = 0; j0 <= q0; j0 += 64) {
    const bool has_next = (j0 + 64 <= q0);
    if (has_next) {
      // T14: issue next tile's loads now; LDS write happens after the barrier
      const unsigned short* kn = kbase + (size_t)(j0 + 64) * DD;
      const unsigned short* vn = vbase + (j0 + 64);
      kr0 = *(const uint4*)(kn);
      kr1 = *(const uint4*)(kn + 8);
      vr0 = *(const uint4*)(vn);
      vr1 = *(const uint4*)(vn + 8);
    }

    // QK^T (q pre-scaled by 1/8 upstream)
    f32x4 s_acc[4] = {{0.f,0.f,0.f,0.f},{0.f,0.f,0.f,0.f},{0.f,0.f,0.f,0.f},{0.f,0.f,0.f,0.f}};
    __builtin_amdgcn_s_setprio(1);
#pragma unroll
    for (int kc = 0; kc < 2; ++kc) {
#pragma unroll
      for (int ct = 0; ct < 4; ++ct) {
        bf16x8 bb = *(const bf16x8*)&Ks[(ct * 16 + l15) * 72 + kc * 32 + koff];
        s_acc[ct] = __builtin_amdgcn_mfma_f32_16x16x32_bf16(aq[kc], bb, s_acc[ct], 0, 0, 0);
      }
    }
    __builtin_amdgcn_s_setprio(0);

    const bool diag = (j0 == q0);
    const int rowbase = q0 + wave * 16 + quad * 4;
#pragma unroll
    for (int r = 0; r < 4; ++r) {
      int qrow = rowbase + r;
      float sv[4];
#pragma unroll
      for (int ct = 0; ct < 4; ++ct) {
        float s = s_acc[ct][r];
        if (diag && (j0 + ct * 16 + l15) > qrow) s = -INFINITY;
        sv[ct] = s;
      }
      float mt = fmaxf(fmaxf(sv[0], sv[1]), fmaxf(sv[2], sv[3]));
      mt = fmaxf(mt, __shfl_xor(mt, 1));
      mt = fmaxf(mt, __shfl_xor(mt, 2));
      mt = fmaxf(mt, __shfl_xor(mt, 4));
      mt = fmaxf(mt, __shfl_xor(mt, 8));
      float mnew = fmaxf(m_run[r], mt);
      float alpha = __expf(m_run[r] - mnew);
      float psum = 0.f;
      int prow = (wave * 16 + quad * 4 + r) * 72;
#pragma unroll
      for (int ct = 0; ct < 4; ++ct) {
        float p = __expf(sv[ct] - mnew);
        psum += p;
        Ps[prow + ct * 16 + l15] = f2bf(p);
      }
      psum += __shfl_xor(psum, 1);
      psum += __shfl_xor(psum, 2);
      psum += __shfl_xor(psum, 4);
      psum += __shfl_xor(psum, 8);
      l_run[r] = l_run[r] * alpha + psum;
      m_run[r] = mnew;
#pragma unroll
      for (int dt = 0; dt < 4; ++dt) o_acc[dt][r] *= alpha;
    }

    // PV  (Ps rows are wave-private: no barrier needed, lgkmcnt orders within-wave)
    __builtin_amdgcn_s_setprio(1);
#pragma unroll
    for (int kc = 0; kc < 2; ++kc) {
      bf16x8 a = *(const bf16x8*)&Ps[(wave * 16 + l15) * 72 + kc * 32 + koff];
#pragma unroll
      for (int dt = 0; dt < 4; ++dt) {
        bf16x8 bb = *(const bf16x8*)&Vt[(dt * 16 + l15) * 72 + kc * 32 + koff];
        o_acc[dt] = __builtin_amdgcn_mfma_f32_16x16x32_bf16(a, bb, o_acc[dt], 0, 0, 0);
      }
    }
    __builtin_amdgcn_s_setprio(0);

    if (has_next) {
      __syncthreads();   // everyone done reading Ks/Vt
      *(uint4*)&Ks[sr * 72 + sc]     = kr0;
      *(uint4*)&Ks[sr * 72 + sc + 8] = kr1;
      *(uint4*)&Vt[sr * 72 + sc]     = vr0;
      *(uint4*)&Vt[sr * 72 + sc + 8] = vr1;
      __syncthreads();   // next tile ready
    }
  }

#pragma unroll
  for (int dt = 0; dt < 4; ++dt) {
#pragma unroll
    for (int r = 0; r < 4; ++r) {
      int row = wave * 16 + quad * 4 + r;
      int t = q0 + row;
      int d = dt * 16 + l15;
      float o = o_acc[dt][r] / l_run[r];
      att[(((size_t)b * TT + t) * HH + h) * DD + d] = f2bf(o);
    }
  }
}

// ---------------------------------------------------------------------------
// Kernel 3: output projection  out[M,384] = att @ Wo + bo
// Same 2-phase double-buffered template + XCD swizzle (1536 = 8 * 64 * 3).
// ---------------------------------------------------------------------------
__global__ __launch_bounds__(256, 2) void oproj128_kernel(const unsigned short* __restrict__ A,
                                                          const unsigned short* __restrict__ Wot,
                                                          const float* __restrict__ bo,
                                                          float* __restrict__ out) {
  const int L = blockIdx.x;
  const int xcd = L & 7;
  const int j = L >> 3;                 // 0..191
  const int mt = xcd * 64 + j / 3;      // 0..511
  const int bx = j % 3;
  const int m0 = mt * 128;
  const int n0 = bx * 128;

  __shared__ char smem[65536];

  const int tid = threadIdx.x;
  const int wave = tid >> 6, lane = tid & 63;
  const int l15 = lane & 15, quad = lane >> 4;
  const int wm = (wave & 1) * 64, wn = (wave >> 1) * 64;
  const int xs = l15 & 7;

  f32x4 acc[4][4];
#pragma unroll
  for (int i = 0; i < 4; ++i)
#pragma unroll
    for (int jj = 0; jj < 4; ++jj) acc[i][jj] = (f32x4){0.f, 0.f, 0.f, 0.f};

  const int rl_base = wave * 32 + (lane >> 3);
  const int sb = lane & 7;

  STAGE_T(0, 0, Wot);
  __syncthreads();
#pragma unroll
  for (int it = 0; it < 6; ++it) {
    if (it < 5) STAGE_T((it & 1) ^ 1, (it + 1) * 64, Wot);
    COMPUTE_T(it & 1);
    __syncthreads();
  }

#pragma unroll
  for (int ni = 0; ni < 4; ++ni) {
    int c = n0 + wn + ni * 16 + l15;
    float bias = bo[c];
#pragma unroll
    for (int mi = 0; mi < 4; ++mi)
#pragma unroll
      for (int r = 0; r < 4; ++r) {
        int m = m0 + wm + mi * 16 + quad * 4 + r;
        out[(size_t)m * EE + c] = acc[mi][ni][r] + bias;
      }
  }
}

// ---------------------------------------------------------------------------
extern "C" void kernel_launch(void* const* d_in, const int* in_sizes, int n_in,
                              void* d_out, int out_size, void* d_ws, size_t ws_size,
                              hipStream_t stream) {
  const float* x  = (const float*)d_in[0];
  const float* Wq = (const float*)d_in[1];
  const float* Wk = (const float*)d_in[2];
  const float* Wv = (const float*)d_in[3];
  const float* Wo = (const float*)d_in[4];
  const float* bo = (const float*)d_in[5];
  float* out = (float*)d_out;

  char* ws = (char*)d_ws;
  const size_t SZ = (size_t)BB * TT * EE * 2;       // 48 MiB
  const size_t SQ = (size_t)BB * HH * TT * DD * 2;  // 48 MiB
  unsigned short* xb = (unsigned short*)ws;          // [B*T, E] bf16
  unsigned short* q  = (unsigned short*)(ws + SZ);
  unsigned short* k  = (unsigned short*)(ws + SZ + SQ);
  unsigned short* v  = (unsigned short*)(ws + SZ + 2 * SQ);
  unsigned short* Wt = (unsigned short*)(ws + SZ + 3 * SQ);  // [1536][384] bf16
  unsigned short* att = xb;  // xb dead after qkv; reuse for attention output

  int n4 = (BB * TT * EE) / 4;
  cvt_kernel<<<(n4 + 255) / 256, 256, 0, stream>>>(x, xb, n4);
  wprep_kernel<<<(1536 * 384 + 255) / 256, 256, 0, stream>>>(Wq, Wk, Wv, Wo, Wt);
  qkv128_kernel<<<dim3(9 * (BB * TT) / 128), 256, 0, stream>>>(xb, Wt, q, k, v);
  attn_kernel<<<dim3(BB * HH, TT / 64), 256, 0, stream>>>(q, k, v, att);
  oproj128_kernel<<<dim3(3 * (BB * TT) / 128), 256, 0, stream>>>(att, Wt + 1152 * 384, bo, out);
}